// Round 1
// baseline (973.405 us; speedup 1.0000x reference)
//
#include <hip/hip_runtime.h>

constexpr int D = 64;

__global__ void k_init_deg(float* __restrict__ deg, int n) {
    int i = blockIdx.x * blockDim.x + threadIdx.x;
    if (i < n) deg[i] = 1.0f;  // self-loop
}

__global__ void k_accum_deg(const int* __restrict__ dst, float* __restrict__ deg, int e) {
    int i = blockIdx.x * blockDim.x + threadIdx.x;
    if (i < e) atomicAdd(&deg[dst[i]], 1.0f);
}

__global__ void k_rsqrt(float* __restrict__ deg, int n) {
    int i = blockIdx.x * blockDim.x + threadIdx.x;
    if (i < n) deg[i] = rsqrtf(deg[i]);
}

// out[row][c] = sum_k act(in[row][k]) * W[k][c];  act = relu if RELU else identity
template <bool RELU>
__global__ void k_dense(const float* __restrict__ in, const float* __restrict__ W,
                        float* __restrict__ out, int n) {
    __shared__ float sW[D][D];  // 16 KB
    int tid = threadIdx.x;      // 256 threads
    for (int i = tid; i < D * D; i += 256) sW[i >> 6][i & 63] = W[i];
    __syncthreads();
    int c = tid & 63;
    int r = tid >> 6;  // 0..3
    for (int row = blockIdx.x * 4 + r; row < n; row += gridDim.x * 4) {
        const float* xr = in + (size_t)row * D;
        float acc = 0.f;
#pragma unroll
        for (int k = 0; k < D; ++k) {
            float xv = xr[k];
            if (RELU) xv = fmaxf(xv, 0.f);
            acc += xv * sW[k][c];
        }
        out[(size_t)row * D + c] = acc;
    }
}

// agg[i][c] = h[i][c]*dinv[i]^2 + b[c]   (self-loop contribution + bias, also inits buffer)
__global__ void k_init_agg(const float* __restrict__ h, const float* __restrict__ dinv,
                           const float* __restrict__ b, float* __restrict__ agg, int n) {
    int idx = blockIdx.x * blockDim.x + threadIdx.x;
    if (idx < n * D) {
        int i = idx >> 6;
        int c = idx & 63;
        float di = dinv[i];
        agg[idx] = h[idx] * di * di + b[c];
    }
}

// for each edge e: agg[dst][c] += h[src][c] * dinv[src]*dinv[dst]
__global__ void k_edge_scatter(const int* __restrict__ src, const int* __restrict__ dst,
                               const float* __restrict__ dinv, const float* __restrict__ h,
                               float* __restrict__ agg, int e) {
    int t = blockIdx.x * blockDim.x + threadIdx.x;
    int edge = t >> 6;
    int c = t & 63;
    if (edge < e) {
        int s = src[edge];
        int d = dst[edge];
        float nrm = dinv[s] * dinv[d];
        atomicAdd(&agg[(size_t)d * D + c], h[(size_t)s * D + c] * nrm);
    }
}

extern "C" void kernel_launch(void* const* d_in, const int* in_sizes, int n_in,
                              void* d_out, int out_size, void* d_ws, size_t ws_size,
                              hipStream_t stream) {
    const float* x  = (const float*)d_in[0];
    const float* W1 = (const float*)d_in[1];
    const float* b1 = (const float*)d_in[2];
    const float* W2 = (const float*)d_in[3];
    const float* b2 = (const float*)d_in[4];
    const int*   ei = (const int*)d_in[5];

    const int n = in_sizes[0] / D;   // 100000
    const int e = in_sizes[5] / 2;   // 1600000
    const int* src = ei;
    const int* dst = ei + e;

    float* out  = (float*)d_out;
    float* dinv = (float*)d_ws;
    float* h    = dinv + n;            // n*4 B offset (16B aligned for n=100000)
    float* agg  = h + (size_t)n * D;

    const int B = 256;

    // degree + normalization
    k_init_deg<<<(n + B - 1) / B, B, 0, stream>>>(dinv, n);
    k_accum_deg<<<(e + B - 1) / B, B, 0, stream>>>(dst, dinv, e);
    k_rsqrt<<<(n + B - 1) / B, B, 0, stream>>>(dinv, n);

    // layer 1: h = x @ W1 ; agg = scatter(h*norm) + b1
    k_dense<false><<<(n + 3) / 4, B, 0, stream>>>(x, W1, h, n);
    k_init_agg<<<((size_t)n * D + B - 1) / B, B, 0, stream>>>(h, dinv, b1, agg, n);
    k_edge_scatter<<<((size_t)e * D + B - 1) / B, B, 0, stream>>>(src, dst, dinv, h, agg, e);

    // layer 2: h = relu(agg) @ W2 ; out = scatter(h*norm) + b2
    k_dense<true><<<(n + 3) / 4, B, 0, stream>>>(agg, W2, h, n);
    k_init_agg<<<((size_t)n * D + B - 1) / B, B, 0, stream>>>(h, dinv, b2, out, n);
    k_edge_scatter<<<((size_t)e * D + B - 1) / B, B, 0, stream>>>(src, dst, dinv, h, out, e);
}

// Round 2
// 461.637 us; speedup vs baseline: 2.1086x; 2.1086x over previous
//
#include <hip/hip_runtime.h>

constexpr int D = 64;

// ---------- CSR build ----------
__global__ void k_zero_cnt(int* __restrict__ cnt, int n) {
    int i = blockIdx.x * blockDim.x + threadIdx.x;
    if (i < n) cnt[i] = 0;
}

__global__ void k_count(const int* __restrict__ dst, int* __restrict__ cnt, int e) {
    int i = blockIdx.x * blockDim.x + threadIdx.x;
    if (i < e) atomicAdd(&cnt[dst[i]], 1);
}

// block-level exclusive scan (1024 elems/block), partial sums to bsum
__global__ void k_scan1(const int* __restrict__ cnt, int* __restrict__ off,
                        int* __restrict__ bsum, int n) {
    __shared__ int s[1024];
    int tid = threadIdx.x, gid = blockIdx.x * 1024 + tid;
    int v = (gid < n) ? cnt[gid] : 0;
    s[tid] = v;
    __syncthreads();
    for (int o = 1; o < 1024; o <<= 1) {
        int t = (tid >= o) ? s[tid - o] : 0;
        __syncthreads();
        s[tid] += t;
        __syncthreads();
    }
    if (gid < n) off[gid] = s[tid] - v;  // exclusive within block
    if (tid == 1023) bsum[blockIdx.x] = s[1023];
}

__global__ void k_scan2(int* __restrict__ bsum, int nb) {
    if (threadIdx.x == 0) {
        int run = 0;
        for (int i = 0; i < nb; ++i) { int v = bsum[i]; bsum[i] = run; run += v; }
    }
}

// finalize offsets, init cursor, compute dinv = rsqrt(deg) with self-loop
__global__ void k_scan3(const int* __restrict__ cnt, int* __restrict__ off,
                        const int* __restrict__ bsum, int* __restrict__ cur,
                        float* __restrict__ dinv, int n, int e) {
    int i = blockIdx.x * blockDim.x + threadIdx.x;
    if (i < n) {
        int o = off[i] + bsum[i >> 10];
        off[i] = o;
        cur[i] = o;
        dinv[i] = rsqrtf((float)(cnt[i] + 1));
        if (i == 0) off[n] = e;
    }
}

// scatter edges into CSR slots; pack {src, norm} as int2 for one dwordx2 load
__global__ void k_fill(const int* __restrict__ src, const int* __restrict__ dst,
                       const float* __restrict__ dinv, int* __restrict__ cur,
                       int2* __restrict__ csr, int e) {
    int i = blockIdx.x * blockDim.x + threadIdx.x;
    if (i < e) {
        int s = src[i], d = dst[i];
        int slot = atomicAdd(&cur[d], 1);
        float nrm = dinv[s] * dinv[d];
        csr[slot] = make_int2(s, __float_as_int(nrm));
    }
}

// ---------- dense transform ----------
// out[row][c] = sum_k act(in[row][k]) * W[k][c];  act = relu if RELU
template <bool RELU>
__global__ void k_dense(const float* __restrict__ in, const float* __restrict__ W,
                        float* __restrict__ out, int n) {
    __shared__ float sW[D][D];  // 16 KB
    int tid = threadIdx.x;      // 256 threads = 4 waves = 4 rows
    for (int i = tid; i < D * D; i += 256) sW[i >> 6][i & 63] = W[i];
    __syncthreads();
    int c = tid & 63;
    int row = blockIdx.x * 4 + (tid >> 6);
    if (row >= n) return;
    const float* xr = in + (size_t)row * D;
    float acc = 0.f;
#pragma unroll
    for (int k = 0; k < D; ++k) {
        float xv = xr[k];
        if (RELU) xv = fmaxf(xv, 0.f);
        acc = fmaf(xv, sW[k][c], acc);
    }
    out[(size_t)row * D + c] = acc;
}

// ---------- CSR gather-aggregate (one wave per node) ----------
// out[i][c] = h[i][c]*dinv[i]^2 + b[c] + sum_{j in row i} h[src_j][c]*nrm_j
__global__ void k_aggregate(const float* __restrict__ h, const float* __restrict__ b,
                            const int* __restrict__ off, const int2* __restrict__ csr,
                            const float* __restrict__ dinv, float* __restrict__ out, int n) {
    int lane = threadIdx.x & 63;
    int node = blockIdx.x * 4 + (threadIdx.x >> 6);
    if (node >= n) return;
    float di = dinv[node];
    float acc = h[(size_t)node * D + lane] * di * di + b[lane];
    int j = off[node], end = off[node + 1];
    for (; j + 3 < end; j += 4) {  // 4 gather rows in flight
        int2 p0 = csr[j], p1 = csr[j + 1], p2 = csr[j + 2], p3 = csr[j + 3];
        float v0 = h[(size_t)p0.x * D + lane];
        float v1 = h[(size_t)p1.x * D + lane];
        float v2 = h[(size_t)p2.x * D + lane];
        float v3 = h[(size_t)p3.x * D + lane];
        acc = fmaf(v0, __int_as_float(p0.y), acc);
        acc = fmaf(v1, __int_as_float(p1.y), acc);
        acc = fmaf(v2, __int_as_float(p2.y), acc);
        acc = fmaf(v3, __int_as_float(p3.y), acc);
    }
    for (; j < end; ++j) {
        int2 p = csr[j];
        acc = fmaf(h[(size_t)p.x * D + lane], __int_as_float(p.y), acc);
    }
    out[(size_t)node * D + lane] = acc;
}

extern "C" void kernel_launch(void* const* d_in, const int* in_sizes, int n_in,
                              void* d_out, int out_size, void* d_ws, size_t ws_size,
                              hipStream_t stream) {
    const float* x  = (const float*)d_in[0];
    const float* W1 = (const float*)d_in[1];
    const float* b1 = (const float*)d_in[2];
    const float* W2 = (const float*)d_in[3];
    const float* b2 = (const float*)d_in[4];
    const int*   ei = (const int*)d_in[5];

    const int n = in_sizes[0] / D;   // 100000
    const int e = in_sizes[5] / 2;   // 1600000
    const int* src = ei;
    const int* dst = ei + e;
    float* out = (float*)d_out;

    // workspace carve-out (256B-aligned chunks), total ~66 MB
    char* base = (char*)d_ws;
    auto alloc = [&](size_t bytes) {
        void* p = (void*)base;
        base += (bytes + 255) & ~(size_t)255;
        return p;
    };
    float* dinv = (float*)alloc((size_t)n * 4);
    int*   cnt  = (int*)alloc((size_t)n * 4);
    int*   off  = (int*)alloc((size_t)(n + 1) * 4);
    int*   cur  = (int*)alloc((size_t)n * 4);
    int*   bsum = (int*)alloc(1024 * 4);
    int2*  csr  = (int2*)alloc((size_t)e * 8);
    float* h    = (float*)alloc((size_t)n * D * 4);
    float* agg  = (float*)alloc((size_t)n * D * 4);

    const int B = 256;
    const int nb = (n + 1023) / 1024;

    // CSR build + normalization
    k_zero_cnt<<<(n + B - 1) / B, B, 0, stream>>>(cnt, n);
    k_count<<<(e + B - 1) / B, B, 0, stream>>>(dst, cnt, e);
    k_scan1<<<nb, 1024, 0, stream>>>(cnt, off, bsum, n);
    k_scan2<<<1, 64, 0, stream>>>(bsum, nb);
    k_scan3<<<(n + B - 1) / B, B, 0, stream>>>(cnt, off, bsum, cur, dinv, n, e);
    k_fill<<<(e + B - 1) / B, B, 0, stream>>>(src, dst, dinv, cur, csr, e);

    // layer 1: h = x @ W1 ; agg = gather-aggregate(h) + b1
    k_dense<false><<<(n + 3) / 4, B, 0, stream>>>(x, W1, h, n);
    k_aggregate<<<(n + 3) / 4, B, 0, stream>>>(h, b1, off, csr, dinv, agg, n);

    // layer 2: h = relu(agg) @ W2 ; out = gather-aggregate(h) + b2
    k_dense<true><<<(n + 3) / 4, B, 0, stream>>>(agg, W2, h, n);
    k_aggregate<<<(n + 3) / 4, B, 0, stream>>>(h, b2, off, csr, dinv, out, n);
}

// Round 3
// 437.542 us; speedup vs baseline: 2.2247x; 1.0551x over previous
//
#include <hip/hip_runtime.h>

constexpr int D = 64;

// ---------- CSR build ----------
__global__ void k_count(const int* __restrict__ dst, int* __restrict__ cnt, int e) {
    int i = blockIdx.x * blockDim.x + threadIdx.x;
    if (i < e) atomicAdd(&cnt[dst[i]], 1);
}

// block-level exclusive scan (1024 elems/block), partial sums to bsum
__global__ void k_scan1(const int* __restrict__ cnt, int* __restrict__ off,
                        int* __restrict__ bsum, int n) {
    __shared__ int s[1024];
    int tid = threadIdx.x, gid = blockIdx.x * 1024 + tid;
    int v = (gid < n) ? cnt[gid] : 0;
    s[tid] = v;
    __syncthreads();
    for (int o = 1; o < 1024; o <<= 1) {
        int t = (tid >= o) ? s[tid - o] : 0;
        __syncthreads();
        s[tid] += t;
        __syncthreads();
    }
    if (gid < n) off[gid] = s[tid] - v;  // exclusive within block
    if (tid == 1023) bsum[blockIdx.x] = s[1023];
}

__global__ void k_scan2(int* __restrict__ bsum, int nb) {
    if (threadIdx.x == 0) {
        int run = 0;
        for (int i = 0; i < nb; ++i) { int v = bsum[i]; bsum[i] = run; run += v; }
    }
}

// finalize offsets, init cursor, compute dinv = rsqrt(deg) with self-loop
__global__ void k_scan3(const int* __restrict__ cnt, int* __restrict__ off,
                        const int* __restrict__ bsum, int* __restrict__ cur,
                        float* __restrict__ dinv, int n, int e) {
    int i = blockIdx.x * blockDim.x + threadIdx.x;
    if (i < n) {
        int o = off[i] + bsum[i >> 10];
        off[i] = o;
        cur[i] = o;
        dinv[i] = rsqrtf((float)(cnt[i] + 1));
        if (i == 0) off[n] = e;
    }
}

// scatter src index into CSR slots (4 B/edge; norm recomputed at gather time)
__global__ void k_fill(const int* __restrict__ src, const int* __restrict__ dst,
                       int* __restrict__ cur, int* __restrict__ csr, int e) {
    int i = blockIdx.x * blockDim.x + threadIdx.x;
    if (i < e) {
        int s = src[i], d = dst[i];
        int slot = atomicAdd(&cur[d], 1);
        csr[slot] = s;
    }
}

// ---------- fused aggregate + dense (one wave per node) ----------
// row_i = dinv[i] * ( act(xin[i])*dinv[i] + sum_j dinv[src_j]*act(xin[src_j]) )
// out_i = row_i @ W + b          (act = relu if RELU)
template <bool RELU>
__global__ void k_agg_mm(const float* __restrict__ xin, const float* __restrict__ W,
                         const float* __restrict__ b,
                         const int* __restrict__ off, const int* __restrict__ csr,
                         const float* __restrict__ dinv, float* __restrict__ out, int n) {
    __shared__ float sW[D][D];   // 16 KB
    __shared__ float sS[4][D];   // per-wave aggregated row staging
    int tid = threadIdx.x;       // 256 threads = 4 waves = 4 nodes
    for (int i = tid; i < D * D; i += 256) sW[i >> 6][i & 63] = W[i];
    int lane = tid & 63;
    int w = tid >> 6;
    int node = blockIdx.x * 4 + w;
    float acc = 0.f;
    if (node < n) {
        float dnode = dinv[node];
        float xv = xin[(size_t)node * D + lane];
        if (RELU) xv = fmaxf(xv, 0.f);
        acc = xv * dnode;  // self-loop term (dinv[node]; outer dnode applied below)
        int j = off[node], end = off[node + 1];
        for (; j + 3 < end; j += 4) {
            int s0 = csr[j], s1 = csr[j + 1], s2 = csr[j + 2], s3 = csr[j + 3];
            float d0 = dinv[s0], d1 = dinv[s1], d2 = dinv[s2], d3 = dinv[s3];
            float v0 = xin[(size_t)s0 * D + lane];
            float v1 = xin[(size_t)s1 * D + lane];
            float v2 = xin[(size_t)s2 * D + lane];
            float v3 = xin[(size_t)s3 * D + lane];
            if (RELU) {
                v0 = fmaxf(v0, 0.f); v1 = fmaxf(v1, 0.f);
                v2 = fmaxf(v2, 0.f); v3 = fmaxf(v3, 0.f);
            }
            acc = fmaf(v0, d0, acc);
            acc = fmaf(v1, d1, acc);
            acc = fmaf(v2, d2, acc);
            acc = fmaf(v3, d3, acc);
        }
        for (; j < end; ++j) {
            int s = csr[j];
            float v = xin[(size_t)s * D + lane];
            if (RELU) v = fmaxf(v, 0.f);
            acc = fmaf(v, dinv[s], acc);
        }
        acc *= dnode;
    }
    sS[w][lane] = acc;
    __syncthreads();
    if (node < n) {
        float o = b[lane];
#pragma unroll
        for (int k = 0; k < D; ++k)
            o = fmaf(sS[w][k], sW[k][lane], o);  // sS broadcast, sW 2-way: conflict-free
        out[(size_t)node * D + lane] = o;
    }
}

extern "C" void kernel_launch(void* const* d_in, const int* in_sizes, int n_in,
                              void* d_out, int out_size, void* d_ws, size_t ws_size,
                              hipStream_t stream) {
    const float* x  = (const float*)d_in[0];
    const float* W1 = (const float*)d_in[1];
    const float* b1 = (const float*)d_in[2];
    const float* W2 = (const float*)d_in[3];
    const float* b2 = (const float*)d_in[4];
    const int*   ei = (const int*)d_in[5];

    const int n = in_sizes[0] / D;   // 100000
    const int e = in_sizes[5] / 2;   // 1600000
    const int* src = ei;
    const int* dst = ei + e;
    float* out = (float*)d_out;

    // workspace carve-out (256B-aligned chunks)
    char* base = (char*)d_ws;
    auto alloc = [&](size_t bytes) {
        void* p = (void*)base;
        base += (bytes + 255) & ~(size_t)255;
        return p;
    };
    float* dinv = (float*)alloc((size_t)n * 4);
    int*   cnt  = (int*)alloc((size_t)n * 4);
    int*   off  = (int*)alloc((size_t)(n + 1) * 4);
    int*   cur  = (int*)alloc((size_t)n * 4);
    int*   bsum = (int*)alloc(1024 * 4);
    int*   csr  = (int*)alloc((size_t)e * 4);
    float* h1   = (float*)alloc((size_t)n * D * 4);

    const int B = 256;
    const int nb = (n + 1023) / 1024;

    // CSR build + normalization
    hipMemsetAsync(cnt, 0, (size_t)n * 4, stream);
    k_count<<<(e + B - 1) / B, B, 0, stream>>>(dst, cnt, e);
    k_scan1<<<nb, 1024, 0, stream>>>(cnt, off, bsum, n);
    k_scan2<<<1, 64, 0, stream>>>(bsum, nb);
    k_scan3<<<(n + B - 1) / B, B, 0, stream>>>(cnt, off, bsum, cur, dinv, n, e);
    k_fill<<<(e + B - 1) / B, B, 0, stream>>>(src, dst, cur, csr, e);

    // layer 1: h1 = (Â x) @ W1 + b1      (aggregate-first via linearity)
    k_agg_mm<false><<<(n + 3) / 4, B, 0, stream>>>(x, W1, b1, off, csr, dinv, h1, n);
    // layer 2: out = (Â relu(h1)) @ W2 + b2
    k_agg_mm<true><<<(n + 3) / 4, B, 0, stream>>>(h1, W2, b2, off, csr, dinv, out, n);
}

// Round 4
// 398.473 us; speedup vs baseline: 2.4428x; 1.0980x over previous
//
#include <hip/hip_runtime.h>

constexpr int D = 64;
constexpr int NBUCK = 8;    // one bucket per XCD
constexpr int NBLK = 1024;  // binning blocks

// ---------- dst-binning (deterministic multisplit, no global atomics) ----------
// pass 1: per-block per-bucket histogram
__global__ void k_bin_hist(const int* __restrict__ dst, int* __restrict__ hist,
                           int e, int bdiv) {
    __shared__ int h[NBUCK];
    if (threadIdx.x < NBUCK) h[threadIdx.x] = 0;
    __syncthreads();
    for (int i = blockIdx.x * blockDim.x + threadIdx.x; i < e; i += gridDim.x * blockDim.x)
        atomicAdd(&h[(unsigned)dst[i] / (unsigned)bdiv], 1);  // LDS atomic
    __syncthreads();
    if (threadIdx.x < NBUCK) hist[threadIdx.x * NBLK + blockIdx.x] = h[threadIdx.x];
}

// pass 2: write edges into per-block private bucket regions (SoA)
__global__ void k_bin_write(const int* __restrict__ src, const int* __restrict__ dst,
                            const int* __restrict__ histS,
                            int* __restrict__ bsrc, int* __restrict__ bdst,
                            int e, int bdiv) {
    __shared__ int cur[NBUCK];
    if (threadIdx.x < NBUCK) cur[threadIdx.x] = histS[threadIdx.x * NBLK + blockIdx.x];
    __syncthreads();
    for (int i = blockIdx.x * blockDim.x + threadIdx.x; i < e; i += gridDim.x * blockDim.x) {
        int s = src[i], d = dst[i];
        int slot = atomicAdd(&cur[(unsigned)d / (unsigned)bdiv], 1);  // LDS atomic
        bsrc[slot] = s;
        bdst[slot] = d;
    }
}

// ---------- generic scan helpers ----------
// block-level exclusive scan (1024 elems/block), partial sums to bsum
__global__ void k_scan1(const int* __restrict__ in, int* __restrict__ out,
                        int* __restrict__ bsum, int n) {
    __shared__ int s[1024];
    int tid = threadIdx.x, gid = blockIdx.x * 1024 + tid;
    int v = (gid < n) ? in[gid] : 0;
    s[tid] = v;
    __syncthreads();
    for (int o = 1; o < 1024; o <<= 1) {
        int t = (tid >= o) ? s[tid - o] : 0;
        __syncthreads();
        s[tid] += t;
        __syncthreads();
    }
    if (gid < n) out[gid] = s[tid] - v;  // exclusive within block
    if (tid == 1023) bsum[blockIdx.x] = s[1023];
}

__global__ void k_scan2(int* __restrict__ bsum, int nb) {
    if (threadIdx.x == 0) {
        int run = 0;
        for (int i = 0; i < nb; ++i) { int v = bsum[i]; bsum[i] = run; run += v; }
    }
}

__global__ void k_finalize(const int* __restrict__ tmp, const int* __restrict__ bsum,
                           int* __restrict__ out, int m) {
    int i = blockIdx.x * blockDim.x + threadIdx.x;
    if (i < m) out[i] = tmp[i] + bsum[i >> 10];
}

// finalize node offsets, init cursor, compute dinv = rsqrt(deg+1)
__global__ void k_scan3(const int* __restrict__ cnt, int* __restrict__ off,
                        const int* __restrict__ bsum, int* __restrict__ cur,
                        float* __restrict__ dinv, int n, int e) {
    int i = blockIdx.x * blockDim.x + threadIdx.x;
    if (i < n) {
        int o = off[i] + bsum[i >> 10];
        off[i] = o;
        cur[i] = o;
        dinv[i] = rsqrtf((float)(cnt[i] + 1));
        if (i == 0) off[n] = e;
    }
}

// ---------- XCD-owned count / fill (bucket p handled by blocks with blockIdx%8==p) ----------
__global__ void k_count_own(const int* __restrict__ bdst, const int* __restrict__ histS,
                            int* __restrict__ cnt, int e) {
    int p = blockIdx.x & (NBUCK - 1);
    int sub = blockIdx.x >> 3;
    int nsub = gridDim.x >> 3;
    int lo = histS[p * NBLK];
    int hi = (p == NBUCK - 1) ? e : histS[(p + 1) * NBLK];
    for (int i = lo + sub * blockDim.x + threadIdx.x; i < hi; i += nsub * blockDim.x)
        atomicAdd(&cnt[bdst[i]], 1);
}

__global__ void k_fill_own(const int* __restrict__ bsrc, const int* __restrict__ bdst,
                           const int* __restrict__ histS, int* __restrict__ cur,
                           int* __restrict__ csr, int e) {
    int p = blockIdx.x & (NBUCK - 1);
    int sub = blockIdx.x >> 3;
    int nsub = gridDim.x >> 3;
    int lo = histS[p * NBLK];
    int hi = (p == NBUCK - 1) ? e : histS[(p + 1) * NBLK];
    for (int i = lo + sub * blockDim.x + threadIdx.x; i < hi; i += nsub * blockDim.x) {
        int d = bdst[i];
        int slot = atomicAdd(&cur[d], 1);
        csr[slot] = bsrc[i];
    }
}

// ---------- fused aggregate + dense (one wave per node) ----------
// row_i = dinv[i] * ( act(xin[i])*dinv[i] + sum_j dinv[src_j]*act(xin[src_j]) )
// out_i = row_i @ W + b          (act = relu if RELU)
template <bool RELU>
__global__ void k_agg_mm(const float* __restrict__ xin, const float* __restrict__ W,
                         const float* __restrict__ b,
                         const int* __restrict__ off, const int* __restrict__ csr,
                         const float* __restrict__ dinv, float* __restrict__ out, int n) {
    __shared__ float sW[D][D];   // 16 KB
    __shared__ float sS[4][D];   // per-wave aggregated row staging
    int tid = threadIdx.x;       // 256 threads = 4 waves = 4 nodes
    for (int i = tid; i < D * D; i += 256) sW[i >> 6][i & 63] = W[i];
    int lane = tid & 63;
    int w = tid >> 6;
    int node = blockIdx.x * 4 + w;
    float acc = 0.f;
    if (node < n) {
        float dnode = dinv[node];
        float xv = xin[(size_t)node * D + lane];
        if (RELU) xv = fmaxf(xv, 0.f);
        acc = xv * dnode;
        int j = off[node], end = off[node + 1];
        for (; j + 3 < end; j += 4) {
            int s0 = csr[j], s1 = csr[j + 1], s2 = csr[j + 2], s3 = csr[j + 3];
            float d0 = dinv[s0], d1 = dinv[s1], d2 = dinv[s2], d3 = dinv[s3];
            float v0 = xin[(size_t)s0 * D + lane];
            float v1 = xin[(size_t)s1 * D + lane];
            float v2 = xin[(size_t)s2 * D + lane];
            float v3 = xin[(size_t)s3 * D + lane];
            if (RELU) {
                v0 = fmaxf(v0, 0.f); v1 = fmaxf(v1, 0.f);
                v2 = fmaxf(v2, 0.f); v3 = fmaxf(v3, 0.f);
            }
            acc = fmaf(v0, d0, acc);
            acc = fmaf(v1, d1, acc);
            acc = fmaf(v2, d2, acc);
            acc = fmaf(v3, d3, acc);
        }
        for (; j < end; ++j) {
            int s = csr[j];
            float v = xin[(size_t)s * D + lane];
            if (RELU) v = fmaxf(v, 0.f);
            acc = fmaf(v, dinv[s], acc);
        }
        acc *= dnode;
    }
    sS[w][lane] = acc;
    __syncthreads();
    if (node < n) {
        float o = b[lane];
#pragma unroll
        for (int k = 0; k < D; ++k)
            o = fmaf(sS[w][k], sW[k][lane], o);  // sS broadcast, sW 2-way alias: conflict-free
        out[(size_t)node * D + lane] = o;
    }
}

extern "C" void kernel_launch(void* const* d_in, const int* in_sizes, int n_in,
                              void* d_out, int out_size, void* d_ws, size_t ws_size,
                              hipStream_t stream) {
    const float* x  = (const float*)d_in[0];
    const float* W1 = (const float*)d_in[1];
    const float* b1 = (const float*)d_in[2];
    const float* W2 = (const float*)d_in[3];
    const float* b2 = (const float*)d_in[4];
    const int*   ei = (const int*)d_in[5];

    const int n = in_sizes[0] / D;   // 100000
    const int e = in_sizes[5] / 2;   // 1600000
    const int* src = ei;
    const int* dst = ei + e;
    float* out = (float*)d_out;
    const int bdiv = (n + NBUCK - 1) / NBUCK;  // dst-range per bucket

    // workspace carve-out (256B-aligned chunks), ~47 MB
    char* base = (char*)d_ws;
    auto alloc = [&](size_t bytes) {
        void* p = (void*)base;
        base += (bytes + 255) & ~(size_t)255;
        return p;
    };
    float* dinv  = (float*)alloc((size_t)n * 4);
    int*   cnt   = (int*)alloc((size_t)n * 4);
    int*   off   = (int*)alloc((size_t)(n + 1) * 4);
    int*   cur   = (int*)alloc((size_t)n * 4);
    int*   bsum  = (int*)alloc(1024 * 4);
    int*   hist  = (int*)alloc((size_t)NBUCK * NBLK * 4);
    int*   histT = (int*)alloc((size_t)NBUCK * NBLK * 4);
    int*   histS = (int*)alloc((size_t)NBUCK * NBLK * 4);
    int*   bsrc  = (int*)alloc((size_t)e * 4);
    int*   bdst  = (int*)alloc((size_t)e * 4);
    int*   csr   = (int*)alloc((size_t)e * 4);
    float* h1    = (float*)alloc((size_t)n * D * 4);

    const int B = 256;
    const int nb = (n + 1023) / 1024;
    const int M = NBUCK * NBLK;  // 8192

    hipMemsetAsync(cnt, 0, (size_t)n * 4, stream);

    // bin edges by dst range (deterministic multisplit)
    k_bin_hist<<<NBLK, B, 0, stream>>>(dst, hist, e, bdiv);
    k_scan1<<<M / 1024, 1024, 0, stream>>>(hist, histT, bsum, M);
    k_scan2<<<1, 64, 0, stream>>>(bsum, M / 1024);
    k_finalize<<<(M + B - 1) / B, B, 0, stream>>>(histT, bsum, histS, M);
    k_bin_write<<<NBLK, B, 0, stream>>>(src, dst, histS, bsrc, bdst, e, bdiv);

    // XCD-owned degree count, then scan -> off/cur/dinv
    k_count_own<<<2048, B, 0, stream>>>(bdst, histS, cnt, e);
    k_scan1<<<nb, 1024, 0, stream>>>(cnt, off, bsum, n);
    k_scan2<<<1, 64, 0, stream>>>(bsum, nb);
    k_scan3<<<(n + B - 1) / B, B, 0, stream>>>(cnt, off, bsum, cur, dinv, n, e);

    // XCD-owned CSR fill
    k_fill_own<<<2048, B, 0, stream>>>(bsrc, bdst, histS, cur, csr, e);

    // layer 1: h1 = (Â x) @ W1 + b1      (aggregate-first via linearity)
    k_agg_mm<false><<<(n + 3) / 4, B, 0, stream>>>(x, W1, b1, off, csr, dinv, h1, n);
    // layer 2: out = (Â relu(h1)) @ W2 + b2
    k_agg_mm<true><<<(n + 3) / 4, B, 0, stream>>>(h1, W2, b2, off, csr, dinv, out, n);
}